// Round 1
// baseline (935.670 us; speedup 1.0000x reference)
//
#include <hip/hip_runtime.h>
#include <math.h>

#define D_GNN 256
#define ATTN 64
#define KNEI 16
#define NROWS 65536

constexpr float EPSV  = 1e-6f;
constexpr float SCALE = 0.125f;   // 64^-0.5

// ---------------------------------------------------------------------------
// K1: M = Wq @ Wk^T   [256,256];  Wq,Wk are [256,64] row-major
// ---------------------------------------------------------------------------
__global__ __launch_bounds__(256) void build_M(const float* __restrict__ Wq,
                                               const float* __restrict__ Wk,
                                               float* __restrict__ M) {
    __shared__ float wq[ATTN];
    int i = blockIdx.x;
    int j = threadIdx.x;
    if (j < ATTN) wq[j] = Wq[i * ATTN + j];
    __syncthreads();
    float s = 0.f;
#pragma unroll
    for (int a = 0; a < ATTN; ++a) s = fmaf(wq[a], Wk[j * ATTN + a], s);
    M[i * D_GNN + j] = s;
}

// ---------------------------------------------------------------------------
// K2: P = C @ M   [65536,256] x [256,256], fp32 tiled GEMM
// block 256 threads, 64x64 tile, 4x4 per thread, BK=32
// ---------------------------------------------------------------------------
__global__ __launch_bounds__(256) void gemm_P(const float* __restrict__ Amat,
                                              const float* __restrict__ Bmat,
                                              float* __restrict__ Cout) {
    const int BM = 64, BN = 64, BK = 32, TM = 4, TN = 4;
    __shared__ float As[BK][BM + 1];
    __shared__ float Bs[BK][BN + 1];
    int tid  = threadIdx.x;
    int tx   = tid & 15;
    int ty   = tid >> 4;
    int brow = blockIdx.x * BM;
    int bcol = blockIdx.y * BN;
    float acc[TM][TN] = {};
    for (int k0 = 0; k0 < D_GNN; k0 += BK) {
#pragma unroll
        for (int li = tid; li < BM * BK; li += 256) {
            int r = li >> 5;       // / BK
            int c = li & 31;       // % BK
            As[c][r] = Amat[(size_t)(brow + r) * D_GNN + k0 + c];
        }
#pragma unroll
        for (int li = tid; li < BK * BN; li += 256) {
            int r = li >> 6;       // / BN
            int c = li & 63;       // % BN
            Bs[r][c] = Bmat[(size_t)(k0 + r) * D_GNN + bcol + c];
        }
        __syncthreads();
#pragma unroll
        for (int kk = 0; kk < BK; ++kk) {
            float a[TM], b[TN];
#pragma unroll
            for (int i = 0; i < TM; ++i) a[i] = As[kk][ty * TM + i];
#pragma unroll
            for (int j = 0; j < TN; ++j) b[j] = Bs[kk][tx * TN + j];
#pragma unroll
            for (int i = 0; i < TM; ++i)
#pragma unroll
                for (int j = 0; j < TN; ++j)
                    acc[i][j] = fmaf(a[i], b[j], acc[i][j]);
        }
        __syncthreads();
    }
#pragma unroll
    for (int i = 0; i < TM; ++i)
#pragma unroll
        for (int j = 0; j < TN; ++j)
            Cout[(size_t)(brow + ty * TM + i) * D_GNN + bcol + tx * TN + j] = acc[i][j];
}

// ---------------------------------------------------------------------------
// K3: gather neighbors, scores = P[b]·neigh * scale + log(w), softmax,
//     weighted sum -> written IN PLACE over P row.
// 1 wave per row, 4 rows per block.
// ---------------------------------------------------------------------------
__global__ __launch_bounds__(256) void gather_attn(float* __restrict__ P,
                                                   const float* __restrict__ allE,
                                                   const int* __restrict__ nidx,
                                                   const float* __restrict__ nw) {
    int lane = threadIdx.x & 63;
    int wid  = threadIdx.x >> 6;
    int b    = blockIdx.x * 4 + wid;

    float4* prow = (float4*)(P + (size_t)b * D_GNN);
    float4 p4 = prow[lane];

    float4 nv[KNEI];
    float  sc[KNEI];
#pragma unroll
    for (int k = 0; k < KNEI; ++k) {
        int idx = nidx[b * KNEI + k];
        const float4* e4 = (const float4*)(allE + (size_t)idx * D_GNN);
        float4 v = e4[lane];
        nv[k] = v;
        sc[k] = p4.x * v.x + p4.y * v.y + p4.z * v.z + p4.w * v.w;
    }
    // full-wave butterfly reduce (all lanes end with the 16 row scores)
#pragma unroll
    for (int k = 0; k < KNEI; ++k) {
        float v = sc[k];
#pragma unroll
        for (int off = 32; off >= 1; off >>= 1) v += __shfl_xor(v, off);
        sc[k] = v;
    }
    float mx = -INFINITY;
    float lw[KNEI];
#pragma unroll
    for (int k = 0; k < KNEI; ++k) {
        float w = nw[b * KNEI + k];
        float s = (w < EPSV) ? -INFINITY : fmaf(sc[k], SCALE, logf(w));
        lw[k] = s;
        mx = fmaxf(mx, s);
    }
    float4 acc = {0.f, 0.f, 0.f, 0.f};
    if (mx > -INFINITY) {
        float den = 0.f;
#pragma unroll
        for (int k = 0; k < KNEI; ++k) {
            float e = expf(lw[k] - mx);   // exp(-inf) = 0 for padded entries
            lw[k] = e;
            den += e;
        }
        float inv = 1.f / den;
#pragma unroll
        for (int k = 0; k < KNEI; ++k) {
            float a = lw[k] * inv;
            acc.x = fmaf(a, nv[k].x, acc.x);
            acc.y = fmaf(a, nv[k].y, acc.y);
            acc.z = fmaf(a, nv[k].z, acc.z);
            acc.w = fmaf(a, nv[k].w, acc.w);
        }
    }
    prow[lane] = acc;   // all-padded row -> zeros (matches nan_to_num)
}

// ---------------------------------------------------------------------------
// K4: gate = sigmoid([C|W] @ Wg + bg); out = gate*C + (1-gate)*W
// [65536,512] x [512,256], same tiling as K2; K runs 0..511 (C half, W half)
// ---------------------------------------------------------------------------
__global__ __launch_bounds__(256) void gate_gemm(const float* __restrict__ Cm,
                                                 const float* __restrict__ Wm,
                                                 const float* __restrict__ Wg,
                                                 const float* __restrict__ bg,
                                                 float* __restrict__ Out) {
    const int BM = 64, BN = 64, BK = 32, TM = 4, TN = 4;
    __shared__ float As[BK][BM + 1];
    __shared__ float Bs[BK][BN + 1];
    int tid  = threadIdx.x;
    int tx   = tid & 15;
    int ty   = tid >> 4;
    int brow = blockIdx.x * BM;
    int bcol = blockIdx.y * BN;
    float acc[TM][TN] = {};
    for (int k0 = 0; k0 < 2 * D_GNN; k0 += BK) {
        const float* Asrc = (k0 < D_GNN) ? Cm : Wm;
        int koff = (k0 < D_GNN) ? k0 : (k0 - D_GNN);
#pragma unroll
        for (int li = tid; li < BM * BK; li += 256) {
            int r = li >> 5;
            int c = li & 31;
            As[c][r] = Asrc[(size_t)(brow + r) * D_GNN + koff + c];
        }
#pragma unroll
        for (int li = tid; li < BK * BN; li += 256) {
            int r = li >> 6;
            int c = li & 63;
            Bs[r][c] = Wg[(size_t)(k0 + r) * D_GNN + bcol + c];
        }
        __syncthreads();
#pragma unroll
        for (int kk = 0; kk < BK; ++kk) {
            float a[TM], b[TN];
#pragma unroll
            for (int i = 0; i < TM; ++i) a[i] = As[kk][ty * TM + i];
#pragma unroll
            for (int j = 0; j < TN; ++j) b[j] = Bs[kk][tx * TN + j];
#pragma unroll
            for (int i = 0; i < TM; ++i)
#pragma unroll
                for (int j = 0; j < TN; ++j)
                    acc[i][j] = fmaf(a[i], b[j], acc[i][j]);
        }
        __syncthreads();
    }
#pragma unroll
    for (int i = 0; i < TM; ++i) {
        size_t r = brow + ty * TM + i;
#pragma unroll
        for (int j = 0; j < TN; ++j) {
            size_t c = bcol + tx * TN + j;
            float g  = 1.f / (1.f + expf(-(acc[i][j] + bg[c])));
            float cv = Cm[r * D_GNN + c];
            float wv = Wm[r * D_GNN + c];
            Out[r * D_GNN + c] = fmaf(g, cv - wv, wv);   // g*c + (1-g)*w
        }
    }
}

// ---------------------------------------------------------------------------
extern "C" void kernel_launch(void* const* d_in, const int* in_sizes, int n_in,
                              void* d_out, int out_size, void* d_ws, size_t ws_size,
                              hipStream_t stream) {
    const float* center = (const float*)d_in[0];
    const float* allE   = (const float*)d_in[1];
    const int*   nidx   = (const int*)d_in[2];
    const float* nw     = (const float*)d_in[3];
    const float* Wq     = (const float*)d_in[4];
    const float* Wk     = (const float*)d_in[5];
    const float* Wg     = (const float*)d_in[6];
    const float* bg     = (const float*)d_in[7];
    float* out = (float*)d_out;

    // ws layout: M [256*256] | P [65536*256] (P is overwritten by weighted sums)
    float* M = (float*)d_ws;
    float* P = M + D_GNN * D_GNN;

    build_M   <<<dim3(D_GNN),               dim3(D_GNN), 0, stream>>>(Wq, Wk, M);
    gemm_P    <<<dim3(NROWS / 64, D_GNN / 64), dim3(256), 0, stream>>>(center, M, P);
    gather_attn<<<dim3(NROWS / 4),          dim3(256),   0, stream>>>(P, allE, nidx, nw);
    gate_gemm <<<dim3(NROWS / 64, D_GNN / 64), dim3(256), 0, stream>>>(center, P, Wg, bg, out);
}

// Round 2
// 259.821 us; speedup vs baseline: 3.6012x; 3.6012x over previous
//
#include <hip/hip_runtime.h>
#include <math.h>

#define D_GNN 256
#define ATTN  64
#define KNEI  16
#define NROWS 65536

constexpr float EPSV  = 1e-6f;
constexpr float SCALE = 0.125f;   // 64^-0.5

typedef __attribute__((ext_vector_type(8))) short bf16x8;
typedef __attribute__((ext_vector_type(4))) float f32x4;

__device__ __forceinline__ unsigned short f2bf(float f) {
    union { float f; unsigned u; } v; v.f = f;
    return (unsigned short)((v.u + 0x7FFFu + ((v.u >> 16) & 1u)) >> 16);
}
__device__ __forceinline__ float bf2f(unsigned short h) {
    union { unsigned u; float f; } v; v.u = ((unsigned)h) << 16;
    return v.f;
}

typedef __attribute__((address_space(3))) short lds_short;
typedef __attribute__((address_space(1))) const short gm_short;
__device__ __forceinline__ void gload16(const unsigned short* g, short* l) {
    __builtin_amdgcn_global_load_lds((gm_short*)g, (lds_short*)l, 16, 0, 0);
}

// ---------------------------------------------------------------------------
// prep: center fp32 -> bf16 (4 elems/thread)
// ---------------------------------------------------------------------------
__global__ __launch_bounds__(256) void conv_C_bf16(const float* __restrict__ in,
                                                   unsigned short* __restrict__ out) {
    size_t i = (size_t)blockIdx.x * 256 + threadIdx.x;
    float4 v = ((const float4*)in)[i];
    short4 o;
    o.x = (short)f2bf(v.x); o.y = (short)f2bf(v.y);
    o.z = (short)f2bf(v.z); o.w = (short)f2bf(v.w);
    ((short4*)out)[i] = o;
}

// ---------------------------------------------------------------------------
// Mt[j][i] = (Wq @ Wk^T)[i][j] in bf16  (stored transposed = B cols k-contig)
// ---------------------------------------------------------------------------
__global__ __launch_bounds__(256) void build_Mt(const float* __restrict__ Wq,
                                                const float* __restrict__ Wk,
                                                unsigned short* __restrict__ Mt) {
    __shared__ float wq[ATTN];
    int i = blockIdx.x;
    int j = threadIdx.x;
    if (j < ATTN) wq[j] = Wq[i * ATTN + j];
    __syncthreads();
    float s = 0.f;
#pragma unroll
    for (int a = 0; a < ATTN; ++a) s = fmaf(wq[a], Wk[j * ATTN + a], s);
    Mt[j * D_GNN + i] = f2bf(s);
}

// ---------------------------------------------------------------------------
// WgT[j][k] = Wg[k][j] in bf16   (j<256, k<512)
// ---------------------------------------------------------------------------
__global__ __launch_bounds__(256) void conv_WgT(const float* __restrict__ Wg,
                                                unsigned short* __restrict__ WgT) {
    int k = blockIdx.x;       // 0..511
    int j = threadIdx.x;      // 0..255
    WgT[j * 512 + k] = f2bf(Wg[k * D_GNN + j]);
}

// ---------------------------------------------------------------------------
// P = Cbf @ Mt^T  -> Pbf [65536,256] bf16.  128x128 tile, BK=64, 4 waves.
// ---------------------------------------------------------------------------
__global__ __launch_bounds__(256) void gemm_P_mfma(const unsigned short* __restrict__ Abf,
                                                   const unsigned short* __restrict__ Bt,
                                                   unsigned short* __restrict__ Pbf) {
    __shared__ short As[128 * 64];
    __shared__ short Bs[128 * 64];
    const int tid  = threadIdx.x;
    const int lane = tid & 63;
    const int wid  = tid >> 6;
    const int wr   = wid >> 1, wc = wid & 1;
    const int l15  = lane & 15, lg = lane >> 4;
    const int brow = blockIdx.x * 128;
    const int bcol = blockIdx.y * 128;

    f32x4 acc[4][4] = {};

    for (int k0 = 0; k0 < D_GNN; k0 += 64) {
#pragma unroll
        for (int is = 0; is < 4; ++is) {
            int off  = is * 4096 + tid * 16;     // byte offset in 16KB tile
            int row  = off >> 7;                 // 128 B per row
            int cs   = (off & 127) >> 1;         // short within row
            int lofs = is * 2048 + wid * 512;    // shorts, wave-uniform
            gload16(Abf + (size_t)(brow + row) * D_GNN + k0 + cs, As + lofs);
            gload16(Bt  + (size_t)(bcol + row) * D_GNN + k0 + cs, Bs + lofs);
        }
        __syncthreads();
#pragma unroll
        for (int kk = 0; kk < 64; kk += 32) {
            bf16x8 af[4], bq[4];
#pragma unroll
            for (int m = 0; m < 4; ++m)
                af[m] = *(const bf16x8*)&As[(wr * 64 + m * 16 + l15) * 64 + kk + lg * 8];
#pragma unroll
            for (int n = 0; n < 4; ++n)
                bq[n] = *(const bf16x8*)&Bs[(wc * 64 + n * 16 + l15) * 64 + kk + lg * 8];
#pragma unroll
            for (int m = 0; m < 4; ++m)
#pragma unroll
                for (int n = 0; n < 4; ++n)
                    acc[m][n] = __builtin_amdgcn_mfma_f32_16x16x32_bf16(af[m], bq[n], acc[m][n], 0, 0, 0);
        }
        __syncthreads();
    }
#pragma unroll
    for (int m = 0; m < 4; ++m) {
        int row0 = brow + wr * 64 + m * 16 + lg * 4;
#pragma unroll
        for (int n = 0; n < 4; ++n) {
            int col = bcol + wc * 64 + n * 16 + l15;
#pragma unroll
            for (int r = 0; r < 4; ++r)
                Pbf[(size_t)(row0 + r) * D_GNN + col] = f2bf(acc[m][n][r]);
        }
    }
}

// ---------------------------------------------------------------------------
// gather + scores + softmax + weighted sum -> Wbf [65536,256] bf16
// 1 wave per row, 4 rows per block
// ---------------------------------------------------------------------------
__global__ __launch_bounds__(256) void gather_attn(const unsigned short* __restrict__ Pbf,
                                                   unsigned short* __restrict__ Wbf,
                                                   const float* __restrict__ allE,
                                                   const int* __restrict__ nidx,
                                                   const float* __restrict__ nw) {
    int lane = threadIdx.x & 63;
    int wid  = threadIdx.x >> 6;
    int b    = blockIdx.x * 4 + wid;

    short4 pq = ((const short4*)(Pbf + (size_t)b * D_GNN))[lane];
    float4 p4 = { bf2f((unsigned short)pq.x), bf2f((unsigned short)pq.y),
                  bf2f((unsigned short)pq.z), bf2f((unsigned short)pq.w) };

    float4 nv[KNEI];
    float  sc[KNEI];
#pragma unroll
    for (int k = 0; k < KNEI; ++k) {
        int idx = nidx[b * KNEI + k];
        float4 v = ((const float4*)(allE + (size_t)idx * D_GNN))[lane];
        nv[k] = v;
        sc[k] = p4.x * v.x + p4.y * v.y + p4.z * v.z + p4.w * v.w;
    }
#pragma unroll
    for (int k = 0; k < KNEI; ++k) {
        float v = sc[k];
#pragma unroll
        for (int off = 32; off >= 1; off >>= 1) v += __shfl_xor(v, off);
        sc[k] = v;
    }
    float mx = -INFINITY;
    float lw[KNEI];
#pragma unroll
    for (int k = 0; k < KNEI; ++k) {
        float w = nw[b * KNEI + k];
        float s = (w < EPSV) ? -INFINITY : fmaf(sc[k], SCALE, logf(w));
        lw[k] = s;
        mx = fmaxf(mx, s);
    }
    float4 acc = {0.f, 0.f, 0.f, 0.f};
    if (mx > -INFINITY) {
        float den = 0.f;
#pragma unroll
        for (int k = 0; k < KNEI; ++k) {
            float e = expf(lw[k] - mx);
            lw[k] = e;
            den += e;
        }
        float inv = 1.f / den;
#pragma unroll
        for (int k = 0; k < KNEI; ++k) {
            float a = lw[k] * inv;
            acc.x = fmaf(a, nv[k].x, acc.x);
            acc.y = fmaf(a, nv[k].y, acc.y);
            acc.z = fmaf(a, nv[k].z, acc.z);
            acc.w = fmaf(a, nv[k].w, acc.w);
        }
    }
    short4 o;
    o.x = (short)f2bf(acc.x); o.y = (short)f2bf(acc.y);
    o.z = (short)f2bf(acc.z); o.w = (short)f2bf(acc.w);
    ((short4*)(Wbf + (size_t)b * D_GNN))[lane] = o;
}

// ---------------------------------------------------------------------------
// gate = sigmoid([C|W] @ Wg + bg); out = g*C + (1-g)*W.  K=512 (C half, W half)
// ---------------------------------------------------------------------------
__global__ __launch_bounds__(256) void gate_gemm_mfma(const unsigned short* __restrict__ Cbf,
                                                      const unsigned short* __restrict__ Wbf,
                                                      const unsigned short* __restrict__ WgT,
                                                      const float* __restrict__ C32,
                                                      const float* __restrict__ bg,
                                                      float* __restrict__ Out) {
    __shared__ short As[128 * 64];
    __shared__ short Bs[128 * 64];
    const int tid  = threadIdx.x;
    const int lane = tid & 63;
    const int wid  = tid >> 6;
    const int wr   = wid >> 1, wc = wid & 1;
    const int l15  = lane & 15, lg = lane >> 4;
    const int brow = blockIdx.x * 128;
    const int bcol = blockIdx.y * 128;

    f32x4 acc[4][4] = {};

    for (int k0 = 0; k0 < 2 * D_GNN; k0 += 64) {
        const unsigned short* Asrc = (k0 < D_GNN) ? Cbf : Wbf;
        int koff = k0 & (D_GNN - 1);
#pragma unroll
        for (int is = 0; is < 4; ++is) {
            int off  = is * 4096 + tid * 16;
            int row  = off >> 7;
            int cs   = (off & 127) >> 1;
            int lofs = is * 2048 + wid * 512;
            gload16(Asrc + (size_t)(brow + row) * D_GNN + koff + cs, As + lofs);
            gload16(WgT  + (size_t)(bcol + row) * 512 + k0 + cs,   Bs + lofs);
        }
        __syncthreads();
#pragma unroll
        for (int kk = 0; kk < 64; kk += 32) {
            bf16x8 af[4], bq[4];
#pragma unroll
            for (int m = 0; m < 4; ++m)
                af[m] = *(const bf16x8*)&As[(wr * 64 + m * 16 + l15) * 64 + kk + lg * 8];
#pragma unroll
            for (int n = 0; n < 4; ++n)
                bq[n] = *(const bf16x8*)&Bs[(wc * 64 + n * 16 + l15) * 64 + kk + lg * 8];
#pragma unroll
            for (int m = 0; m < 4; ++m)
#pragma unroll
                for (int n = 0; n < 4; ++n)
                    acc[m][n] = __builtin_amdgcn_mfma_f32_16x16x32_bf16(af[m], bq[n], acc[m][n], 0, 0, 0);
        }
        __syncthreads();
    }
#pragma unroll
    for (int m = 0; m < 4; ++m) {
        int row0 = brow + wr * 64 + m * 16 + lg * 4;
#pragma unroll
        for (int n = 0; n < 4; ++n) {
            int col = bcol + wc * 64 + n * 16 + l15;
            float bgc = bg[col];
#pragma unroll
            for (int r = 0; r < 4; ++r) {
                size_t rr = (size_t)(row0 + r);
                float g  = 1.f / (1.f + expf(-(acc[m][n][r] + bgc)));
                float cv = C32[rr * D_GNN + col];
                float wv = bf2f(Wbf[rr * D_GNN + col]);
                Out[rr * D_GNN + col] = fmaf(g, cv - wv, wv);
            }
        }
    }
}

// ---------------------------------------------------------------------------
extern "C" void kernel_launch(void* const* d_in, const int* in_sizes, int n_in,
                              void* d_out, int out_size, void* d_ws, size_t ws_size,
                              hipStream_t stream) {
    const float* center = (const float*)d_in[0];
    const float* allE   = (const float*)d_in[1];
    const int*   nidx   = (const int*)d_in[2];
    const float* nw     = (const float*)d_in[3];
    const float* Wq     = (const float*)d_in[4];
    const float* Wk     = (const float*)d_in[5];
    const float* Wg     = (const float*)d_in[6];
    const float* bg     = (const float*)d_in[7];
    float* out = (float*)d_out;

    // ws layout (bf16): Cbf | Wbf | Pbf | Mt | WgT   (~96.3 MB total)
    unsigned short* Cbf = (unsigned short*)d_ws;
    unsigned short* Wbf = Cbf + (size_t)NROWS * D_GNN;
    unsigned short* Pbf = Wbf + (size_t)NROWS * D_GNN;
    unsigned short* Mt  = Pbf + (size_t)NROWS * D_GNN;
    unsigned short* WgT = Mt + D_GNN * D_GNN;

    conv_C_bf16   <<<dim3(NROWS * D_GNN / 1024), dim3(256), 0, stream>>>(center, Cbf);
    build_Mt      <<<dim3(D_GNN),                dim3(256), 0, stream>>>(Wq, Wk, Mt);
    conv_WgT      <<<dim3(2 * D_GNN),            dim3(256), 0, stream>>>(Wg, WgT);
    gemm_P_mfma   <<<dim3(NROWS / 128, 2),       dim3(256), 0, stream>>>(Cbf, Mt, Pbf);
    gather_attn   <<<dim3(NROWS / 4),            dim3(256), 0, stream>>>(Pbf, Wbf, allE, nidx, nw);
    gate_gemm_mfma<<<dim3(NROWS / 128, 2),       dim3(256), 0, stream>>>(Cbf, Wbf, WgT, center, bg, out);
}